// Round 1
// baseline (313.698 us; speedup 1.0000x reference)
//
#include <hip/hip_runtime.h>

typedef __attribute__((ext_vector_type(4))) float f32x4;
typedef __attribute__((ext_vector_type(8))) short bf16x8;
typedef unsigned long long u64;
typedef unsigned short u16;
typedef unsigned int u32;

// round-to-nearest-even f32 -> bf16 bits
static __device__ __forceinline__ u16 f2bf(float f) {
    u32 u = __float_as_uint(f);
    u += 0x7fffu + ((u >> 16) & 1u);
    return (u16)(u >> 16);
}

// ---------------- kernel 1: s[g][ic] = style[g] . mod_w[ic] + mod_b[ic] ----
__global__ void k_style(const float* __restrict__ style, const float* __restrict__ mod_w,
                        const float* __restrict__ mod_b, float* __restrict__ s_ws) {
    int t = blockIdx.x * 256 + threadIdx.x;     // 0..2047
    int g = t >> 9, ic = t & 511;
    const f32x4* st = (const f32x4*)(style + (g << 9));
    const f32x4* mw = (const f32x4*)(mod_w + (ic << 9));
    float acc = 0.f;
#pragma unroll 4
    for (int d = 0; d < 128; ++d) {
        f32x4 a = st[d], b = mw[d];
        acc += a[0]*b[0] + a[1]*b[1] + a[2]*b[2] + a[3]*b[3];
    }
    s_ws[t] = acc + mod_b[ic];
}

// ---------------- kernel 2: Wmod bf16 [g][tap][oc][ic] ---------------------
__global__ void k_wmod(const float* __restrict__ weight, const float* __restrict__ demod,
                       const float* __restrict__ s_ws, short* __restrict__ wmod) {
    int t = blockIdx.x * 256 + threadIdx.x;     // over 4*512*512
    int ic = t & 511, oc = (t >> 9) & 511, g = t >> 18;
    float sv = s_ws[(g << 9) + ic] * demod[ic];
    const float* wp = weight + ((size_t)((oc << 9) + ic)) * 9;
#pragma unroll
    for (int tap = 0; tap < 9; ++tap) {
        size_t idx = ((size_t)((g * 9 + tap) * 512 + oc) << 9) + ic;
        wmod[idx] = (short)f2bf(wp[tap] * sv);
    }
}

// ---------------- kernel 3: main implicit-GEMM conv ------------------------
// Block tile: 128 oc x 256 px (4 image rows). BK = 64 ic. 9 taps outer.
// LDS: Xs[(4+2 halo rows)*66 padded px][64 ic] bf16, transposed+swizzled.
//      Ws[128 oc][64 ic] bf16, swizzled.
// 4 waves, each computes 64 oc x 128 px = 4x8 fragments of 16x16.
__global__ __launch_bounds__(256, 2) void k_conv(const float* __restrict__ x,
                                                 const short* __restrict__ wmod,
                                                 float* __restrict__ out) {
    __shared__ __align__(16) short Xs[396 * 64];   // 50688 B
    __shared__ __align__(16) short Ws[128 * 64];   // 16384 B

    const int tid  = threadIdx.x;
    const int lane = tid & 63;
    const int wv   = tid >> 6;
    const int wr   = wv >> 1, wc = wv & 1;
    const int l15  = lane & 15;
    const int l4   = lane >> 4;
    const int rowb = blockIdx.x & 15, ocb = blockIdx.x >> 4;
    const int g    = blockIdx.y, nb = blockIdx.z;
    const int y0   = rowb << 2;

    const float* xg = x + (((size_t)(nb * 2048 + (g << 9))) << 12);
    const short* wg = wmod + (size_t)g * (9 * 512 * 512) + ((size_t)(ocb * 128) << 9);
    float* outg = out + (((size_t)(nb * 2048 + (g << 9) + ocb * 128)) << 12) + (rowb << 8);

    // zero Xs once: pads (cols 0,65 of each padded row) + out-of-image halo rows stay 0
    for (int i = tid; i < 6336; i += 256) ((u64*)Xs)[i] = 0ull;

    f32x4 acc[4][8];
#pragma unroll
    for (int m = 0; m < 4; ++m)
#pragma unroll
        for (int nn = 0; nn < 8; ++nn) acc[m][nn] = (f32x4){0.f, 0.f, 0.f, 0.f};

    for (int ch = 0; ch < 8; ++ch) {
        const int ic0 = ch << 6;
        __syncthreads();   // previous chunk's reads of Xs/Ws complete

        // ---- stage X: fp32 -> bf16, transposed [p][ic], 16B-block swizzle ----
        {
            const int q = tid & 15, icg4 = tid >> 4;   // 4 px, 4 ic per thread per row
#pragma unroll
            for (int r = 0; r < 6; ++r) {
                const int gy = y0 - 1 + r;
                if (gy >= 0 && gy <= 63) {
                    const float* src = xg + (((size_t)(ic0 + (icg4 << 2))) << 12) + (gy << 6) + (q << 2);
                    f32x4 v0 = *(const f32x4*)(src);
                    f32x4 v1 = *(const f32x4*)(src + 4096);
                    f32x4 v2 = *(const f32x4*)(src + 8192);
                    f32x4 v3 = *(const f32x4*)(src + 12288);
                    const int pb = r * 66 + 1 + (q << 2);
#pragma unroll
                    for (int c = 0; c < 4; ++c) {
                        const int p = pb + c;
                        u64 pk = (u64)f2bf(v0[c]) | ((u64)f2bf(v1[c]) << 16)
                               | ((u64)f2bf(v2[c]) << 32) | ((u64)f2bf(v3[c]) << 48);
                        const int blk = (icg4 >> 1) ^ (p & 7);
                        *(u64*)&Xs[(p << 6) + (blk << 3) + ((icg4 & 1) << 2)] = pk;
                    }
                }
            }
        }

        for (int tap = 0; tap < 9; ++tap) {
            if (tap) __syncthreads();   // prior MFMA reads of Ws done
            // ---- stage Ws[128][64] for this (chunk, tap), swizzled ----
#pragma unroll
            for (int it = 0; it < 4; ++it) {
                const int j = tid + (it << 8);
                const int blk = j & 7, oc = j >> 3;
                bf16x8 w8 = *(const bf16x8*)&wg[tap * 262144 + (oc << 9) + ic0 + (blk << 3)];
                *(bf16x8*)&Ws[(oc << 6) + ((blk ^ (oc & 7)) << 3)] = w8;
            }
            __syncthreads();

            const int dy = tap / 3 - 1, dx = tap % 3 - 1;
#pragma unroll
            for (int kk = 0; kk < 2; ++kk) {
                const int bblk = (kk << 2) + l4;
                bf16x8 a[4], b[8];
#pragma unroll
                for (int m = 0; m < 4; ++m) {
                    const int oc = (wr << 6) + (m << 4) + l15;
                    a[m] = *(const bf16x8*)&Ws[(oc << 6) + ((bblk ^ (oc & 7)) << 3)];
                }
#pragma unroll
                for (int nn = 0; nn < 8; ++nn) {
                    const int j = (wc << 7) + (nn << 4) + l15;
                    const int p = ((j >> 6) + 1 + dy) * 66 + (j & 63) + 1 + dx;
                    b[nn] = *(const bf16x8*)&Xs[(p << 6) + ((bblk ^ (p & 7)) << 3)];
                }
#pragma unroll
                for (int m = 0; m < 4; ++m)
#pragma unroll
                    for (int nn = 0; nn < 8; ++nn)
                        acc[m][nn] = __builtin_amdgcn_mfma_f32_16x16x32_bf16(a[m], b[nn], acc[m][nn], 0, 0, 0);
            }
        }
    }

    // ---- epilogue: C/D layout col=lane&15 (pixel), row=(lane>>4)*4+r (oc) ----
#pragma unroll
    for (int m = 0; m < 4; ++m)
#pragma unroll
        for (int nn = 0; nn < 8; ++nn) {
            const int oc = (wr << 6) + (m << 4) + (l4 << 2);
            const int p  = (wc << 7) + (nn << 4) + l15;
            float* dst = outg + ((size_t)oc << 12) + p;
#pragma unroll
            for (int r = 0; r < 4; ++r) dst[(size_t)r << 12] = acc[m][nn][r];
        }
}

extern "C" void kernel_launch(void* const* d_in, const int* in_sizes, int n_in,
                              void* d_out, int out_size, void* d_ws, size_t ws_size,
                              hipStream_t stream) {
    const float* x      = (const float*)d_in[0];
    const float* style  = (const float*)d_in[1];
    const float* weight = (const float*)d_in[2];
    const float* demod  = (const float*)d_in[3];
    const float* mod_w  = (const float*)d_in[4];
    const float* mod_b  = (const float*)d_in[5];
    float* out = (float*)d_out;

    float* s_ws = (float*)d_ws;                         // 4*512 f32 = 8 KB
    short* wmod = (short*)((char*)d_ws + 8192);         // 4*9*512*512 bf16 = 18.9 MB

    hipLaunchKernelGGL(k_style, dim3(8), dim3(256), 0, stream, style, mod_w, mod_b, s_ws);
    hipLaunchKernelGGL(k_wmod, dim3(4096), dim3(256), 0, stream, weight, demod, s_ws, wmod);
    hipLaunchKernelGGL(k_conv, dim3(64, 4, 4), dim3(256), 0, stream, x, wmod, out);
}